// Round 2
// baseline (588.938 us; speedup 1.0000x reference)
//
#include <hip/hip_runtime.h>
#include <cstdint>
#include <cstddef>

#define B_  4
#define L_  4096
#define N_  1024
#define D_  768
#define H_  12
#define HD_ 64

typedef __bf16 bf16x8 __attribute__((ext_vector_type(8)));
typedef float  f32x4  __attribute__((ext_vector_type(4)));

static __device__ __forceinline__ f32x4 mfma16(bf16x8 a, bf16x8 b, f32x4 c) {
    return __builtin_amdgcn_mfma_f32_16x16x32_bf16(a, b, c, 0, 0, 0);
}

// fp32 -> bf16 elementwise cast, 4 elems/thread (n divisible by 4)
__global__ __launch_bounds__(256) void cast_kernel(const float* __restrict__ in,
                                                   __bf16* __restrict__ out, int n)
{
    const int i = (blockIdx.x * 256 + threadIdx.x) * 4;
    if (i >= n) return;
    const float4 v = *(const float4*)(in + i);
    out[i + 0] = (__bf16)v.x;
    out[i + 1] = (__bf16)v.y;
    out[i + 2] = (__bf16)v.z;
    out[i + 3] = (__bf16)v.w;
}

// out[o][i] = W[o][i] + 2 * sum_r Bm[o][r] * Am[r][i]   (fold LoRA into weight), fp32 in, bf16 out
__global__ __launch_bounds__(256) void weff_kernel(const float* __restrict__ W,
                                                   const float* __restrict__ Bm,
                                                   const float* __restrict__ Am,
                                                   __bf16* __restrict__ out)
{
    const int idx = blockIdx.x * 256 + threadIdx.x;   // < 768*768
    const int o = idx / D_, i = idx - o * D_;
    float s = 0.f;
#pragma unroll
    for (int r = 0; r < 8; ++r)
        s += Bm[o * 8 + r] * Am[r * D_ + i];
    out[idx] = (__bf16)(W[idx] + 2.0f * s);
}

// LayerNorm over last dim (768); one block per row. fp32 in, bf16 out.
__global__ __launch_bounds__(256) void ln_kernel(const float* __restrict__ x,
                                                 const float* __restrict__ g,
                                                 const float* __restrict__ be,
                                                 __bf16* __restrict__ y)
{
    const int row = blockIdx.x, tid = threadIdx.x;
    const int lane = tid & 63, wid = tid >> 6;
    const float* xr = x + (size_t)row * D_;
    float v[3];
    float s = 0.f, s2 = 0.f;
#pragma unroll
    for (int j = 0; j < 3; ++j) {
        v[j] = xr[tid + j * 256];
        s += v[j];
        s2 += v[j] * v[j];
    }
#pragma unroll
    for (int off = 32; off > 0; off >>= 1) {
        s  += __shfl_down(s, off);
        s2 += __shfl_down(s2, off);
    }
    __shared__ float red[8];
    if (lane == 0) { red[wid] = s; red[4 + wid] = s2; }
    __syncthreads();
    s  = red[0] + red[1] + red[2] + red[3];
    s2 = red[4] + red[5] + red[6] + red[7];
    const float mean = s * (1.f / D_);
    const float var  = s2 * (1.f / D_) - mean * mean;
    const float rstd = rsqrtf(var + 1e-5f);
    __bf16* yr = y + (size_t)row * D_;
#pragma unroll
    for (int j = 0; j < 3; ++j) {
        const int i = tid + j * 256;
        yr[i] = (__bf16)((v[j] - mean) * rstd * g[i] + be[i]);
    }
}

// C[m][o] = sum_k A[m][k] * W[o][k]   (A, W bf16; fp32 accum)
// EPI==0: bf16 store (row-major, stride 768)
// EPI==1: bf16 store transposed into Vt (B,H,HD,N)   [m = b*1024+n, o = h*64+d]
// EPI==2: add fp32 resid[m][o] + fp32 bias[o], fp32 row-major store
template <int EPI, typename CT>
__global__ __launch_bounds__(256) void gemm_nt(const __bf16* __restrict__ A,
                                               const __bf16* __restrict__ W,
                                               CT* __restrict__ C,
                                               const float* __restrict__ resid,
                                               const float* __restrict__ bias)
{
    const int tid = threadIdx.x, wid = tid >> 6, lane = tid & 63;
    const int lr = lane & 15, lg = lane >> 4;
    const int mb = blockIdx.x * 128 + (wid >> 1) * 64;
    const int ob = blockIdx.y * 128 + (wid & 1) * 64;

    f32x4 acc[4][4] = {};

    const __bf16* arow = A + (size_t)(mb + lr) * D_ + lg * 8;
    const __bf16* wrow = W + (size_t)(ob + lr) * D_ + lg * 8;

    for (int k = 0; k < D_; k += 32) {
        bf16x8 av[4], wv[4];
#pragma unroll
        for (int mi = 0; mi < 4; ++mi)
            av[mi] = *(const bf16x8*)(arow + (size_t)mi * 16 * D_ + k);
#pragma unroll
        for (int oi = 0; oi < 4; ++oi)
            wv[oi] = *(const bf16x8*)(wrow + (size_t)oi * 16 * D_ + k);
#pragma unroll
        for (int mi = 0; mi < 4; ++mi)
#pragma unroll
            for (int oi = 0; oi < 4; ++oi)
                acc[mi][oi] = mfma16(av[mi], wv[oi], acc[mi][oi]);
    }

#pragma unroll
    for (int mi = 0; mi < 4; ++mi) {
#pragma unroll
        for (int oi = 0; oi < 4; ++oi) {
#pragma unroll
            for (int r = 0; r < 4; ++r) {
                const int m = mb + mi * 16 + lg * 4 + r;
                const int o = ob + oi * 16 + lr;
                float v = acc[mi][oi][r];
                if (EPI == 2)
                    v += resid[(size_t)m * D_ + o] + bias[o];
                if (EPI == 1) {
                    const size_t idx =
                        ((size_t)((m >> 10) * H_ + (o >> 6)) * HD_ + (o & 63)) * N_ + (m & (N_ - 1));
                    C[idx] = (CT)v;
                } else {
                    C[(size_t)m * D_ + o] = (CT)v;
                }
            }
        }
    }
}

// Flash attention: block = (b, h, 64 queries), 4 waves x 16-query strips.
// Q:(B,L,D) bf16, K:(B,N,D) bf16, Vt:(B,H,HD,N) bf16, mask:(B,N) int
__global__ __launch_bounds__(256) void attn_kernel(const __bf16* __restrict__ Qb,
                                                   const __bf16* __restrict__ Kb,
                                                   const __bf16* __restrict__ Vt,
                                                   const int* __restrict__ mask,
                                                   __bf16* __restrict__ ctx)
{
    const int bq = blockIdx.x, h = blockIdx.y, b = blockIdx.z;
    const int tid = threadIdx.x, wid = tid >> 6, lane = tid & 63;
    const int lr = lane & 15, lg = lane >> 4;

    __shared__ float maskadd[N_];
    __shared__ __align__(16) __bf16 p_lds[4][16][40];  // per-wave 16x32 P, rows padded

    for (int i = tid; i < N_; i += 256)
        maskadd[i] = (mask[b * N_ + i] != 0) ? 0.f : -1e30f;
    __syncthreads();

    const int q0 = bq * 64 + wid * 16;
    const __bf16* qptr = Qb + ((size_t)b * L_ + q0 + lr) * D_ + h * HD_ + lg * 8;
    const bf16x8 qa0 = *(const bf16x8*)(qptr);
    const bf16x8 qa1 = *(const bf16x8*)(qptr + 32);

    f32x4 acc[4] = {};
    float mrun[4], ssum[4];
#pragma unroll
    for (int r = 0; r < 4; ++r) { mrun[r] = -1e30f; ssum[r] = 0.f; }

    const __bf16* kbase = Kb + ((size_t)b * N_ + lr) * D_ + h * HD_ + lg * 8;
    const __bf16* vbase = Vt + (((size_t)b * H_ + h) * HD_ + lr) * N_ + lg * 8;

    for (int n0 = 0; n0 < N_; n0 += 32) {
        const __bf16* kp = kbase + (size_t)n0 * D_;
        const bf16x8 k00 = *(const bf16x8*)(kp);
        const bf16x8 k01 = *(const bf16x8*)(kp + 32);
        const bf16x8 k10 = *(const bf16x8*)(kp + (size_t)16 * D_);
        const bf16x8 k11 = *(const bf16x8*)(kp + (size_t)16 * D_ + 32);

        f32x4 z = {};
        f32x4 s0 = mfma16(qa0, k00, z); s0 = mfma16(qa1, k01, s0);
        f32x4 s1 = mfma16(qa0, k10, z); s1 = mfma16(qa1, k11, s1);

        const float ms0 = maskadd[n0 + lr];
        const float ms1 = maskadd[n0 + 16 + lr];
        float p0[4], p1[4], tmax[4], tsum[4];
#pragma unroll
        for (int r = 0; r < 4; ++r) {
            p0[r] = s0[r] * 0.125f + ms0;
            p1[r] = s1[r] * 0.125f + ms1;
            tmax[r] = fmaxf(p0[r], p1[r]);
        }
#pragma unroll
        for (int off = 1; off < 16; off <<= 1)
#pragma unroll
            for (int r = 0; r < 4; ++r)
                tmax[r] = fmaxf(tmax[r], __shfl_xor(tmax[r], off));
#pragma unroll
        for (int r = 0; r < 4; ++r) {
            const float newm = fmaxf(mrun[r], tmax[r]);
            const float alpha = __expf(mrun[r] - newm);
            mrun[r] = newm;
            p0[r] = __expf(p0[r] - newm);
            p1[r] = __expf(p1[r] - newm);
            tsum[r] = p0[r] + p1[r];
            ssum[r] *= alpha;
#pragma unroll
            for (int dt = 0; dt < 4; ++dt) acc[dt][r] *= alpha;
        }
#pragma unroll
        for (int off = 1; off < 16; off <<= 1)
#pragma unroll
            for (int r = 0; r < 4; ++r)
                tsum[r] += __shfl_xor(tsum[r], off);
#pragma unroll
        for (int r = 0; r < 4; ++r) ssum[r] += tsum[r];

        // transpose P (16q x 32n) into A-fragment layout via per-wave LDS
#pragma unroll
        for (int r = 0; r < 4; ++r) {
            p_lds[wid][lg * 4 + r][lr]      = (__bf16)p0[r];
            p_lds[wid][lg * 4 + r][16 + lr] = (__bf16)p1[r];
        }
        __syncthreads();
        const bf16x8 pa = *(const bf16x8*)&p_lds[wid][lr][lg * 8];

#pragma unroll
        for (int dt = 0; dt < 4; ++dt) {
            const bf16x8 vb = *(const bf16x8*)(vbase + (size_t)(dt * 16) * N_ + n0);
            acc[dt] = mfma16(pa, vb, acc[dt]);
        }
        __syncthreads();
    }

    float inv[4];
#pragma unroll
    for (int r = 0; r < 4; ++r)
        inv[r] = (mrun[r] > -1e29f && ssum[r] > 0.f) ? 1.f / ssum[r] : 0.f;
#pragma unroll
    for (int dt = 0; dt < 4; ++dt)
#pragma unroll
        for (int r = 0; r < 4; ++r) {
            const int q = q0 + lg * 4 + r;
            const int d = dt * 16 + lr;
            ctx[((size_t)b * L_ + q) * D_ + h * HD_ + d] = (__bf16)(acc[dt][r] * inv[r]);
        }
}

extern "C" void kernel_launch(void* const* d_in, const int* in_sizes, int n_in,
                              void* d_out, int out_size, void* d_ws, size_t ws_size,
                              hipStream_t stream)
{
    const float* text    = (const float*)d_in[0];
    const float* regions = (const float*)d_in[1];
    const int*   mask    = (const int*)d_in[2];
    const float* Wq  = (const float*)d_in[3];
    const float* Aq  = (const float*)d_in[4];
    const float* Bq  = (const float*)d_in[5];
    const float* Wk  = (const float*)d_in[6];
    const float* Wv  = (const float*)d_in[7];
    const float* Av  = (const float*)d_in[8];
    const float* Bv  = (const float*)d_in[9];
    const float* Wo  = (const float*)d_in[10];
    const float* bo  = (const float*)d_in[11];
    const float* gq  = (const float*)d_in[12];
    const float* bq  = (const float*)d_in[13];
    const float* gkv = (const float*)d_in[14];
    const float* bkv = (const float*)d_in[15];

    const size_t BLD = (size_t)B_ * L_ * D_;   // 12,582,912
    const size_t BND = (size_t)B_ * N_ * D_;   //  3,145,728
    const size_t DD  = (size_t)D_ * D_;        //    589,824
    __bf16* ws   = (__bf16*)d_ws;
    __bf16* tq   = ws;                 // BLD
    __bf16* rk   = tq + BLD;           // BND
    __bf16* Qb   = rk + BND;           // BLD
    __bf16* Kb   = Qb + BLD;           // BND
    __bf16* Vt   = Kb + BND;           // BND
    __bf16* ctx  = Vt + BND;           // BLD
    __bf16* regb = ctx + BLD;          // BND
    __bf16* Weq  = regb + BND;         // DD
    __bf16* Wev  = Weq + DD;           // DD
    __bf16* Wkb  = Wev + DD;           // DD
    __bf16* Wob  = Wkb + DD;           // DD

    weff_kernel<<<dim3(DD / 256), 256, 0, stream>>>(Wq, Bq, Aq, Weq);
    weff_kernel<<<dim3(DD / 256), 256, 0, stream>>>(Wv, Bv, Av, Wev);
    cast_kernel<<<dim3(DD / 1024), 256, 0, stream>>>(Wk, Wkb, (int)DD);
    cast_kernel<<<dim3(DD / 1024), 256, 0, stream>>>(Wo, Wob, (int)DD);
    cast_kernel<<<dim3(BND / 1024), 256, 0, stream>>>(regions, regb, (int)BND);
    ln_kernel<<<dim3(B_ * L_), 256, 0, stream>>>(text, gq, bq, tq);
    ln_kernel<<<dim3(B_ * N_), 256, 0, stream>>>(regions, gkv, bkv, rk);
    gemm_nt<0, __bf16><<<dim3((B_ * L_) / 128, D_ / 128), 256, 0, stream>>>(tq, Weq, Qb, nullptr, nullptr);
    gemm_nt<0, __bf16><<<dim3((B_ * N_) / 128, D_ / 128), 256, 0, stream>>>(rk, Wkb, Kb, nullptr, nullptr);
    gemm_nt<1, __bf16><<<dim3((B_ * N_) / 128, D_ / 128), 256, 0, stream>>>(regb, Wev, Vt, nullptr, nullptr);
    attn_kernel<<<dim3(L_ / 64, H_, B_), 256, 0, stream>>>(Qb, Kb, Vt, mask, ctx);
    gemm_nt<2, float><<<dim3((B_ * L_) / 128, D_ / 128), 256, 0, stream>>>(ctx, Wob, (float*)d_out, text, bo);
}

// Round 3
// 333.393 us; speedup vs baseline: 1.7665x; 1.7665x over previous
//
#include <hip/hip_runtime.h>
#include <cstdint>
#include <cstddef>

#define B_  4
#define L_  4096
#define N_  1024
#define D_  768
#define H_  12
#define HD_ 64

typedef __bf16 bf16x8 __attribute__((ext_vector_type(8)));
typedef float  f32x4  __attribute__((ext_vector_type(4)));
typedef unsigned int u32;

static __device__ __forceinline__ f32x4 mfma16(bf16x8 a, bf16x8 b, f32x4 c) {
    return __builtin_amdgcn_mfma_f32_16x16x32_bf16(a, b, c, 0, 0, 0);
}

static __device__ __forceinline__ void async_cp16(const __bf16* g, __bf16* l) {
    __builtin_amdgcn_global_load_lds(
        (const __attribute__((address_space(1))) u32*)g,
        (__attribute__((address_space(3))) u32*)l, 16, 0, 0);
}

static __device__ __forceinline__ u32 pkbf(float lo, float hi) {
    union { __bf16 b[2]; u32 u; } r;
    r.b[0] = (__bf16)lo; r.b[1] = (__bf16)hi;
    return r.u;
}

// fp32 -> bf16 elementwise cast, 4 elems/thread
__global__ __launch_bounds__(256) void cast_kernel(const float* __restrict__ in,
                                                   __bf16* __restrict__ out, int n)
{
    const int i = (blockIdx.x * 256 + threadIdx.x) * 4;
    if (i >= n) return;
    const float4 v = *(const float4*)(in + i);
    out[i + 0] = (__bf16)v.x;
    out[i + 1] = (__bf16)v.y;
    out[i + 2] = (__bf16)v.z;
    out[i + 3] = (__bf16)v.w;
}

// out[o][i] = W[o][i] + 2 * sum_r Bm[o][r] * Am[r][i]
__global__ __launch_bounds__(256) void weff_kernel(const float* __restrict__ W,
                                                   const float* __restrict__ Bm,
                                                   const float* __restrict__ Am,
                                                   __bf16* __restrict__ out)
{
    const int idx = blockIdx.x * 256 + threadIdx.x;
    const int o = idx / D_, i = idx - o * D_;
    float s = 0.f;
#pragma unroll
    for (int r = 0; r < 8; ++r)
        s += Bm[o * 8 + r] * Am[r * D_ + i];
    out[idx] = (__bf16)(W[idx] + 2.0f * s);
}

// LayerNorm over last dim (768); one block per row. fp32 in, bf16 out.
__global__ __launch_bounds__(256) void ln_kernel(const float* __restrict__ x,
                                                 const float* __restrict__ g,
                                                 const float* __restrict__ be,
                                                 __bf16* __restrict__ y)
{
    const int row = blockIdx.x, tid = threadIdx.x;
    const int lane = tid & 63, wid = tid >> 6;
    const float* xr = x + (size_t)row * D_;
    float v[3];
    float s = 0.f, s2 = 0.f;
#pragma unroll
    for (int j = 0; j < 3; ++j) {
        v[j] = xr[tid + j * 256];
        s += v[j];
        s2 += v[j] * v[j];
    }
#pragma unroll
    for (int off = 32; off > 0; off >>= 1) {
        s  += __shfl_down(s, off);
        s2 += __shfl_down(s2, off);
    }
    __shared__ float red[8];
    if (lane == 0) { red[wid] = s; red[4 + wid] = s2; }
    __syncthreads();
    s  = red[0] + red[1] + red[2] + red[3];
    s2 = red[4] + red[5] + red[6] + red[7];
    const float mean = s * (1.f / D_);
    const float var  = s2 * (1.f / D_) - mean * mean;
    const float rstd = rsqrtf(var + 1e-5f);
    __bf16* yr = y + (size_t)row * D_;
#pragma unroll
    for (int j = 0; j < 3; ++j) {
        const int i = tid + j * 256;
        yr[i] = (__bf16)((v[j] - mean) * rstd * g[i] + be[i]);
    }
}

// C[m][o] = sum_k A[m][k] * W[o][k]   (bf16 in, fp32 accum)
// EPI==0: bf16 row-major store | EPI==1: bf16 store transposed (B,H,HD,N)
// EPI==2: +resid+bias, fp32 store | EPI==3: *0.125, bf16 row-major store
template <int EPI, typename CT>
__global__ __launch_bounds__(256) void gemm_nt(const __bf16* __restrict__ A,
                                               const __bf16* __restrict__ W,
                                               CT* __restrict__ C,
                                               const float* __restrict__ resid,
                                               const float* __restrict__ bias)
{
    const int tid = threadIdx.x, wid = tid >> 6, lane = tid & 63;
    const int lr = lane & 15, lg = lane >> 4;
    const int mb = blockIdx.x * 128 + (wid >> 1) * 64;
    const int ob = blockIdx.y * 128 + (wid & 1) * 64;

    f32x4 acc[4][4] = {};

    const __bf16* arow = A + (size_t)(mb + lr) * D_ + lg * 8;
    const __bf16* wrow = W + (size_t)(ob + lr) * D_ + lg * 8;

    for (int k = 0; k < D_; k += 32) {
        bf16x8 av[4], wv[4];
#pragma unroll
        for (int mi = 0; mi < 4; ++mi)
            av[mi] = *(const bf16x8*)(arow + (size_t)mi * 16 * D_ + k);
#pragma unroll
        for (int oi = 0; oi < 4; ++oi)
            wv[oi] = *(const bf16x8*)(wrow + (size_t)oi * 16 * D_ + k);
#pragma unroll
        for (int mi = 0; mi < 4; ++mi)
#pragma unroll
            for (int oi = 0; oi < 4; ++oi)
                acc[mi][oi] = mfma16(av[mi], wv[oi], acc[mi][oi]);
    }

#pragma unroll
    for (int mi = 0; mi < 4; ++mi) {
#pragma unroll
        for (int oi = 0; oi < 4; ++oi) {
#pragma unroll
            for (int r = 0; r < 4; ++r) {
                const int m = mb + mi * 16 + lg * 4 + r;
                const int o = ob + oi * 16 + lr;
                float v = acc[mi][oi][r];
                if (EPI == 2)
                    v += resid[(size_t)m * D_ + o] + bias[o];
                if (EPI == 3)
                    v *= 0.125f;
                if (EPI == 1) {
                    const size_t idx =
                        ((size_t)((m >> 10) * H_ + (o >> 6)) * HD_ + (o & 63)) * N_ + (m & (N_ - 1));
                    C[idx] = (CT)v;
                } else {
                    C[(size_t)m * D_ + o] = (CT)v;
                }
            }
        }
    }
}

// Flash attention, swapped-QK^T, in-register softmax, LDS-staged K/V.
// Block = (b, h, 64 q), 4 waves x 16 q. Q pre-scaled by 0.125 in Q-GEMM.
// Q:(B,L,D) bf16, K:(B,N,D) bf16, Vt:(B,H,HD,N) bf16, mask:(B,N) int
__global__ __launch_bounds__(256, 3) void attn_kernel(const __bf16* __restrict__ Qb,
                                                      const __bf16* __restrict__ Kb,
                                                      const __bf16* __restrict__ Vt,
                                                      const int* __restrict__ mask,
                                                      __bf16* __restrict__ ctx)
{
    const int bq = blockIdx.x, h = blockIdx.y, b = blockIdx.z;
    const int tid = threadIdx.x, wid = tid >> 6, lane = tid & 63;
    const int lr = lane & 15, g = lane >> 4;

    __shared__ float maskadd[N_];
    __shared__ __align__(16) __bf16 kbuf[2][4096];   // [2] x 64 keys x 64 d (slot-swizzled)
    __shared__ __align__(16) __bf16 vbuf[2][4096];   // [2] x 64 d x 64 keys (slot-swizzled)

    for (int i = tid; i < N_; i += 256)
        maskadd[i] = (mask[b * N_ + i] != 0) ? 0.f : -1e30f;

    const int hoff = h * HD_;
    const int bN = b * N_;
    const size_t bhHD = ((size_t)b * H_ + h) * HD_;

    // per-lane staging geometry: slot s -> row=s>>3, 16B-slot sl=s&7, src slot = sl^(row&7)
    const int s_base = wid * 64 + lane;

    auto stage = [&](int t, int bsel) {
        const int n0 = t * 64;
#pragma unroll
        for (int j = 0; j < 2; ++j) {
            const int s = s_base + j * 256;
            const int row = s >> 3;
            const int ks = (s & 7) ^ (row & 7);
            async_cp16(Kb + ((size_t)(bN + n0 + row) * D_ + hoff + ks * 8),
                       &kbuf[bsel][(wid * 64 + j * 256) * 8]);
            async_cp16(Vt + (bhHD + row) * N_ + n0 + ks * 8,
                       &vbuf[bsel][(wid * 64 + j * 256) * 8]);
        }
    };

    const int q0 = bq * 64 + wid * 16;
    const __bf16* qptr = Qb + ((size_t)b * L_ + q0 + lr) * D_ + hoff + g * 8;
    const bf16x8 qa0 = *(const bf16x8*)(qptr);
    const bf16x8 qa1 = *(const bf16x8*)(qptr + 32);

    f32x4 acc[4] = {};
    float mrun = 0.f, ssum = 0.f;
    const int x7 = lr & 7;

    stage(0, 0);
    asm volatile("s_waitcnt vmcnt(0)" ::: "memory");
    __syncthreads();

    for (int t = 0; t < 16; ++t) {
        const int buf = t & 1;
        if (t < 15) stage(t + 1, buf ^ 1);

        const __bf16* kb = kbuf[buf];
        const __bf16* vb = vbuf[buf];

        // K fragments: tile kt rows are permuted so lane's S values == its PV keys
        bf16x8 kf[4][2];
#pragma unroll
        for (int kt = 0; kt < 4; ++kt) {
            const int row = (kt >> 1) * 32 + (lr >> 2) * 8 + (kt & 1) * 4 + (lr & 3);
            const int rx = row & 7;
#pragma unroll
            for (int kc = 0; kc < 2; ++kc)
                kf[kt][kc] = *(const bf16x8*)((const char*)kb + row * 128 + ((((kc * 4) + g) ^ rx) << 4));
        }

        // S^T = K·Q^T : lane holds q=lr, keys (kt>>1)*32 + g*8 + (kt&1)*4 + r
        f32x4 s4[4];
#pragma unroll
        for (int kt = 0; kt < 4; ++kt) {
            f32x4 z = {};
            s4[kt] = mfma16(kf[kt][0], qa0, z);
            s4[kt] = mfma16(kf[kt][1], qa1, s4[kt]);
        }

        float p[4][4];
        float pmax = -3e38f;
#pragma unroll
        for (int kt = 0; kt < 4; ++kt) {
            const float4 mv = *(const float4*)&maskadd[t * 64 + (kt >> 1) * 32 + g * 8 + (kt & 1) * 4];
            p[kt][0] = s4[kt][0] + mv.x;
            p[kt][1] = s4[kt][1] + mv.y;
            p[kt][2] = s4[kt][2] + mv.z;
            p[kt][3] = s4[kt][3] + mv.w;
#pragma unroll
            for (int r = 0; r < 4; ++r) pmax = fmaxf(pmax, p[kt][r]);
        }
        pmax = fmaxf(pmax, __shfl_xor(pmax, 16));
        pmax = fmaxf(pmax, __shfl_xor(pmax, 32));

        if (__any(pmax > mrun + 8.f)) {           // defer-max: rare
            const float newm = fmaxf(mrun, pmax);
            const float alpha = __expf(mrun - newm);
            ssum *= alpha;
            float av[4];
#pragma unroll
            for (int r = 0; r < 4; ++r) av[r] = __shfl(alpha, g * 4 + r);
#pragma unroll
            for (int dt = 0; dt < 4; ++dt)
#pragma unroll
                for (int r = 0; r < 4; ++r) acc[dt][r] *= av[r];
            mrun = newm;
        }

        float tsum = 0.f;
#pragma unroll
        for (int kt = 0; kt < 4; ++kt)
#pragma unroll
            for (int r = 0; r < 4; ++r) {
                p[kt][r] = __expf(p[kt][r] - mrun);
                tsum += p[kt][r];
            }
        tsum += __shfl_xor(tsum, 16);
        tsum += __shfl_xor(tsum, 32);
        ssum += tsum;

        // pack P into PV A-fragments (no cross-lane needed by construction)
        bf16x8 pa[2];
#pragma unroll
        for (int c = 0; c < 2; ++c) {
            union { u32 w[4]; bf16x8 v; } pu;
#pragma unroll
            for (int m = 0; m < 4; ++m) {
                const int kt = 2 * c + (m >> 1);
                pu.w[m] = pkbf(p[kt][2 * (m & 1)], p[kt][2 * (m & 1) + 1]);
            }
            pa[c] = pu.v;
        }

#pragma unroll
        for (int dt = 0; dt < 4; ++dt) {
            const int d = dt * 16 + lr;
#pragma unroll
            for (int c = 0; c < 2; ++c) {
                const bf16x8 vf = *(const bf16x8*)((const char*)vb + d * 128 + ((((c * 4) + g) ^ x7) << 4));
                acc[dt] = mfma16(pa[c], vf, acc[dt]);
            }
        }

        asm volatile("s_waitcnt vmcnt(0)" ::: "memory");
        __syncthreads();
    }

    const float inv = (ssum > 0.f) ? 1.f / ssum : 0.f;
    float iv[4];
#pragma unroll
    for (int r = 0; r < 4; ++r) iv[r] = __shfl(inv, g * 4 + r);

#pragma unroll
    for (int dt = 0; dt < 4; ++dt)
#pragma unroll
        for (int r = 0; r < 4; ++r) {
            const int q = q0 + g * 4 + r;
            ctx[((size_t)b * L_ + q) * D_ + hoff + dt * 16 + lr] = (__bf16)(acc[dt][r] * iv[r]);
        }
}

extern "C" void kernel_launch(void* const* d_in, const int* in_sizes, int n_in,
                              void* d_out, int out_size, void* d_ws, size_t ws_size,
                              hipStream_t stream)
{
    const float* text    = (const float*)d_in[0];
    const float* regions = (const float*)d_in[1];
    const int*   mask    = (const int*)d_in[2];
    const float* Wq  = (const float*)d_in[3];
    const float* Aq  = (const float*)d_in[4];
    const float* Bq  = (const float*)d_in[5];
    const float* Wk  = (const float*)d_in[6];
    const float* Wv  = (const float*)d_in[7];
    const float* Av  = (const float*)d_in[8];
    const float* Bv  = (const float*)d_in[9];
    const float* Wo  = (const float*)d_in[10];
    const float* bo  = (const float*)d_in[11];
    const float* gq  = (const float*)d_in[12];
    const float* bq  = (const float*)d_in[13];
    const float* gkv = (const float*)d_in[14];
    const float* bkv = (const float*)d_in[15];

    const size_t BLD = (size_t)B_ * L_ * D_;
    const size_t BND = (size_t)B_ * N_ * D_;
    const size_t DD  = (size_t)D_ * D_;
    __bf16* ws   = (__bf16*)d_ws;
    __bf16* tq   = ws;                 // BLD
    __bf16* rk   = tq + BLD;           // BND
    __bf16* Qb   = rk + BND;           // BLD
    __bf16* Kb   = Qb + BLD;           // BND
    __bf16* Vt   = Kb + BND;           // BND
    __bf16* ctx  = Vt + BND;           // BLD
    __bf16* regb = ctx + BLD;          // BND
    __bf16* Weq  = regb + BND;         // DD
    __bf16* Wev  = Weq + DD;           // DD
    __bf16* Wkb  = Wev + DD;           // DD
    __bf16* Wob  = Wkb + DD;           // DD

    weff_kernel<<<dim3(DD / 256), 256, 0, stream>>>(Wq, Bq, Aq, Weq);
    weff_kernel<<<dim3(DD / 256), 256, 0, stream>>>(Wv, Bv, Av, Wev);
    cast_kernel<<<dim3(DD / 1024), 256, 0, stream>>>(Wk, Wkb, (int)DD);
    cast_kernel<<<dim3(DD / 1024), 256, 0, stream>>>(Wo, Wob, (int)DD);
    cast_kernel<<<dim3(BND / 1024), 256, 0, stream>>>(regions, regb, (int)BND);
    ln_kernel<<<dim3(B_ * L_), 256, 0, stream>>>(text, gq, bq, tq);
    ln_kernel<<<dim3(B_ * N_), 256, 0, stream>>>(regions, gkv, bkv, rk);
    gemm_nt<3, __bf16><<<dim3((B_ * L_) / 128, D_ / 128), 256, 0, stream>>>(tq, Weq, Qb, nullptr, nullptr);
    gemm_nt<0, __bf16><<<dim3((B_ * N_) / 128, D_ / 128), 256, 0, stream>>>(rk, Wkb, Kb, nullptr, nullptr);
    gemm_nt<1, __bf16><<<dim3((B_ * N_) / 128, D_ / 128), 256, 0, stream>>>(regb, Wev, Vt, nullptr, nullptr);
    attn_kernel<<<dim3(L_ / 64, H_, B_), 256, 0, stream>>>(Qb, Kb, Vt, mask, ctx);
    gemm_nt<2, float><<<dim3((B_ * L_) / 128, D_ / 128), 256, 0, stream>>>(ctx, Wob, (float*)d_out, text, bo);
}

// Round 4
// 209.810 us; speedup vs baseline: 2.8070x; 1.5890x over previous
//
#include <hip/hip_runtime.h>
#include <cstdint>
#include <cstddef>

#define B_  4
#define L_  4096
#define N_  1024
#define D_  768
#define H_  12
#define HD_ 64

typedef __bf16 bf16x8 __attribute__((ext_vector_type(8)));
typedef float  f32x4  __attribute__((ext_vector_type(4)));
typedef unsigned int u32;

static __device__ __forceinline__ f32x4 mfma16(bf16x8 a, bf16x8 b, f32x4 c) {
    return __builtin_amdgcn_mfma_f32_16x16x32_bf16(a, b, c, 0, 0, 0);
}

static __device__ __forceinline__ void async_cp16(const __bf16* g, const __bf16* l) {
    __builtin_amdgcn_global_load_lds(
        (const __attribute__((address_space(1))) u32*)g,
        (__attribute__((address_space(3))) u32*)l, 16, 0, 0);
}

static __device__ __forceinline__ u32 pkbf(float lo, float hi) {
    union { __bf16 b[2]; u32 u; } r;
    r.b[0] = (__bf16)lo; r.b[1] = (__bf16)hi;
    return r.u;
}

// fp32 -> bf16 elementwise cast, 4 elems/thread
__global__ __launch_bounds__(256) void cast_kernel(const float* __restrict__ in,
                                                   __bf16* __restrict__ out, int n)
{
    const int i = (blockIdx.x * 256 + threadIdx.x) * 4;
    if (i >= n) return;
    const float4 v = *(const float4*)(in + i);
    out[i + 0] = (__bf16)v.x;
    out[i + 1] = (__bf16)v.y;
    out[i + 2] = (__bf16)v.z;
    out[i + 3] = (__bf16)v.w;
}

// out[o][i] = W[o][i] + 2 * sum_r Bm[o][r] * Am[r][i]
__global__ __launch_bounds__(256) void weff_kernel(const float* __restrict__ W,
                                                   const float* __restrict__ Bm,
                                                   const float* __restrict__ Am,
                                                   __bf16* __restrict__ out)
{
    const int idx = blockIdx.x * 256 + threadIdx.x;
    const int o = idx / D_, i = idx - o * D_;
    float s = 0.f;
#pragma unroll
    for (int r = 0; r < 8; ++r)
        s += Bm[o * 8 + r] * Am[r * D_ + i];
    out[idx] = (__bf16)(W[idx] + 2.0f * s);
}

// LayerNorm over last dim (768); one block per row. fp32 in, bf16 out.
__global__ __launch_bounds__(256) void ln_kernel(const float* __restrict__ x,
                                                 const float* __restrict__ g,
                                                 const float* __restrict__ be,
                                                 __bf16* __restrict__ y)
{
    const int row = blockIdx.x, tid = threadIdx.x;
    const int lane = tid & 63, wid = tid >> 6;
    const float* xr = x + (size_t)row * D_;
    float v[3];
    float s = 0.f, s2 = 0.f;
#pragma unroll
    for (int j = 0; j < 3; ++j) {
        v[j] = xr[tid + j * 256];
        s += v[j];
        s2 += v[j] * v[j];
    }
#pragma unroll
    for (int off = 32; off > 0; off >>= 1) {
        s  += __shfl_down(s, off);
        s2 += __shfl_down(s2, off);
    }
    __shared__ float red[8];
    if (lane == 0) { red[wid] = s; red[4 + wid] = s2; }
    __syncthreads();
    s  = red[0] + red[1] + red[2] + red[3];
    s2 = red[4] + red[5] + red[6] + red[7];
    const float mean = s * (1.f / D_);
    const float var  = s2 * (1.f / D_) - mean * mean;
    const float rstd = rsqrtf(var + 1e-5f);
    __bf16* yr = y + (size_t)row * D_;
#pragma unroll
    for (int j = 0; j < 3; ++j) {
        const int i = tid + j * 256;
        yr[i] = (__bf16)((v[j] - mean) * rstd * g[i] + be[i]);
    }
}

// LDS-staged 128x128 GEMM body (m97 structure). C[m][o] = sum_k A[m][k]*W[o][k].
// sm: 16384 bf16 of dynamic LDS (A0 B0 A1 B1, each 128x32).
// EPI==0: bf16 row-major | EPI==1: bf16 transposed (B,H,HD,N) | EPI==2: +resid+bias fp32 | EPI==3: *0.125 bf16
template <int EPI, typename CT>
static __device__ __forceinline__ void gemm_body(__bf16* sm,
                                                 const __bf16* __restrict__ A,
                                                 const __bf16* __restrict__ W,
                                                 CT* __restrict__ C,
                                                 const float* __restrict__ resid,
                                                 const float* __restrict__ bias,
                                                 int mb0, int nb0)
{
    const int tid = threadIdx.x, wid = tid >> 6, lane = tid & 63;
    const int lr = lane & 15, g = lane >> 4;
    const int wm = wid >> 1, wn = wid & 1;

    auto stage = [&](int kb, int buf) {
        __bf16* as = sm + buf * 8192;
        __bf16* bs = as + 4096;
#pragma unroll
        for (int j = 0; j < 2; ++j) {
            const int s = wid * 64 + lane + j * 256;
            const int row = s >> 2, c16 = s & 3;
            const int dst = (wid * 64 + j * 256) * 8;
            async_cp16(A + (size_t)(mb0 + row) * D_ + kb * 32 + c16 * 8, as + dst);
            async_cp16(W + (size_t)(nb0 + row) * D_ + kb * 32 + c16 * 8, bs + dst);
        }
    };

    f32x4 acc[4][4] = {};

    stage(0, 0);
    asm volatile("s_waitcnt vmcnt(0)" ::: "memory");
    __syncthreads();

    for (int kb = 0; kb < D_ / 32; ++kb) {
        const int buf = kb & 1;
        if (kb < D_ / 32 - 1) stage(kb + 1, buf ^ 1);
        const __bf16* as = sm + buf * 8192;
        const __bf16* bs = as + 4096;
        bf16x8 av[4], wv[4];
#pragma unroll
        for (int mi = 0; mi < 4; ++mi)
            av[mi] = *(const bf16x8*)(as + (wm * 64 + mi * 16 + lr) * 32 + g * 8);
#pragma unroll
        for (int oi = 0; oi < 4; ++oi)
            wv[oi] = *(const bf16x8*)(bs + (wn * 64 + oi * 16 + lr) * 32 + g * 8);
#pragma unroll
        for (int mi = 0; mi < 4; ++mi)
#pragma unroll
            for (int oi = 0; oi < 4; ++oi)
                acc[mi][oi] = mfma16(av[mi], wv[oi], acc[mi][oi]);
        asm volatile("s_waitcnt vmcnt(0)" ::: "memory");
        __syncthreads();
    }

#pragma unroll
    for (int mi = 0; mi < 4; ++mi) {
#pragma unroll
        for (int oi = 0; oi < 4; ++oi) {
#pragma unroll
            for (int r = 0; r < 4; ++r) {
                const int m = mb0 + wm * 64 + mi * 16 + g * 4 + r;
                const int o = nb0 + wn * 64 + oi * 16 + lr;
                float v = acc[mi][oi][r];
                if (EPI == 2)
                    v += resid[(size_t)m * D_ + o] + bias[o];
                if (EPI == 3)
                    v *= 0.125f;
                if (EPI == 1) {
                    const size_t idx =
                        ((size_t)((m >> 10) * H_ + (o >> 6)) * HD_ + (o & 63)) * N_ + (m & (N_ - 1));
                    C[idx] = (CT)v;
                } else {
                    C[(size_t)m * D_ + o] = (CT)v;
                }
            }
        }
    }
}

template <int EPI, typename CT>
__global__ __launch_bounds__(256) void gemm_nt(const __bf16* __restrict__ A,
                                               const __bf16* __restrict__ W,
                                               CT* __restrict__ C,
                                               const float* __restrict__ resid,
                                               const float* __restrict__ bias)
{
    extern __shared__ __bf16 smem[];
    gemm_body<EPI, CT>(smem, A, W, C, resid, bias, blockIdx.x * 128, blockIdx.y * 128);
}

// Fused K-GEMM + V-GEMM (each M=4096): bx<32 -> K, else V(transposed store)
__global__ __launch_bounds__(256) void gemm_kv(const __bf16* __restrict__ rk,
                                               const __bf16* __restrict__ Wkb,
                                               const __bf16* __restrict__ regb,
                                               const __bf16* __restrict__ Wev,
                                               __bf16* __restrict__ Kb,
                                               __bf16* __restrict__ Vt)
{
    extern __shared__ __bf16 smem[];
    if (blockIdx.x < 32)
        gemm_body<0, __bf16>(smem, rk, Wkb, Kb, nullptr, nullptr, blockIdx.x * 128, blockIdx.y * 128);
    else
        gemm_body<1, __bf16>(smem, regb, Wev, Vt, nullptr, nullptr, (blockIdx.x - 32) * 128, blockIdx.y * 128);
}

// Flash attention, swapped-QK^T, in-register softmax, LDS-staged K/V.
// Block = (b, h, 128 q), 4 waves x 32 q. Q pre-scaled by 0.125 in Q-GEMM.
// Q:(B,L,D) bf16, K:(B,N,D) bf16, Vt:(B,H,HD,N) bf16, mask:(B,N) int
__global__ __launch_bounds__(256, 3) void attn_kernel(const __bf16* __restrict__ Qb,
                                                      const __bf16* __restrict__ Kb,
                                                      const __bf16* __restrict__ Vt,
                                                      const int* __restrict__ mask,
                                                      __bf16* __restrict__ ctx)
{
    const int bq = blockIdx.x, h = blockIdx.y, b = blockIdx.z;
    const int tid = threadIdx.x, wid = tid >> 6, lane = tid & 63;
    const int lr = lane & 15, g = lane >> 4;

    __shared__ float maskadd[N_];
    __shared__ __align__(16) __bf16 kbuf[2][4096];   // [2] x 64 keys x 64 d (slot-swizzled)
    __shared__ __align__(16) __bf16 vbuf[2][4096];   // [2] x 64 d x 64 keys (slot-swizzled)

    for (int i = tid; i < N_; i += 256)
        maskadd[i] = (mask[b * N_ + i] != 0) ? 0.f : -1e30f;

    const int hoff = h * HD_;
    const int bN = b * N_;
    const size_t bhHD = ((size_t)b * H_ + h) * HD_;

    // slot-swizzle key: spreads the 16 concurrently-read rows over all 8 slots
    auto skey = [](int row) { return (row & 3) | (((row >> 3) & 1) << 2); };

    auto stage = [&](int t, int bsel) {
        const int n0 = t * 64;
#pragma unroll
        for (int j = 0; j < 2; ++j) {
            const int s = wid * 64 + lane + j * 256;
            const int row = s >> 3;
            const int ks = (s & 7) ^ skey(row);
            const int dst = (wid * 64 + j * 256) * 8;
            async_cp16(Kb + ((size_t)(bN + n0 + row) * D_ + hoff + ks * 8), &kbuf[bsel][dst]);
            async_cp16(Vt + (bhHD + row) * N_ + n0 + ks * 8, &vbuf[bsel][dst]);
        }
    };

    const int q0 = bq * 128 + wid * 32;
    bf16x8 qa[2][2];
#pragma unroll
    for (int qf = 0; qf < 2; ++qf) {
        const __bf16* qptr = Qb + ((size_t)b * L_ + q0 + qf * 16 + lr) * D_ + hoff + g * 8;
        qa[qf][0] = *(const bf16x8*)(qptr);
        qa[qf][1] = *(const bf16x8*)(qptr + 32);
    }

    f32x4 acc[2][4] = {};
    float mrun[2] = {0.f, 0.f}, ssum[2] = {0.f, 0.f};

    stage(0, 0);
    asm volatile("s_waitcnt vmcnt(0)" ::: "memory");
    __syncthreads();

    for (int t = 0; t < 16; ++t) {
        const int buf = t & 1;
        if (t < 15) stage(t + 1, buf ^ 1);

        const __bf16* kb = kbuf[buf];
        const __bf16* vb = vbuf[buf];

        // mask additive terms for this tile (same for both q-frags)
        f32x4 mv[4];
#pragma unroll
        for (int kt = 0; kt < 4; ++kt)
            mv[kt] = *(const f32x4*)&maskadd[t * 64 + (kt >> 1) * 32 + g * 8 + (kt & 1) * 4];

        // K fragments: rows permuted so lane's S values == its PV A-fragment keys
        bf16x8 kf[4][2];
#pragma unroll
        for (int kt = 0; kt < 4; ++kt) {
            const int row = (kt >> 1) * 32 + (lr >> 2) * 8 + (kt & 1) * 4 + (lr & 3);
            const int kx = skey(row);
#pragma unroll
            for (int kc = 0; kc < 2; ++kc)
                kf[kt][kc] = *(const bf16x8*)((const char*)kb + row * 128 + ((((kc * 4) + g) ^ kx) << 4));
        }

        bf16x8 pa[2][2];
#pragma unroll
        for (int qf = 0; qf < 2; ++qf) {
            // S^T = K·Q^T : lane holds q=lr (within strip), keys (kt>>1)*32 + g*8 + (kt&1)*4 + r
            f32x4 s4[4];
#pragma unroll
            for (int kt = 0; kt < 4; ++kt) {
                f32x4 z = {};
                s4[kt] = mfma16(kf[kt][0], qa[qf][0], z);
                s4[kt] = mfma16(kf[kt][1], qa[qf][1], s4[kt]);
            }

            float p[4][4];
            float pmax = -3e38f;
#pragma unroll
            for (int kt = 0; kt < 4; ++kt)
#pragma unroll
                for (int r = 0; r < 4; ++r) {
                    p[kt][r] = s4[kt][r] + mv[kt][r];
                    pmax = fmaxf(pmax, p[kt][r]);
                }
            pmax = fmaxf(pmax, __shfl_xor(pmax, 16));
            pmax = fmaxf(pmax, __shfl_xor(pmax, 32));

            if (__any(pmax > mrun[qf] + 8.f)) {       // defer-max: rare
                const float newm = fmaxf(mrun[qf], pmax);
                const float alpha = __expf(mrun[qf] - newm);
                ssum[qf] *= alpha;
                float av[4];
#pragma unroll
                for (int r = 0; r < 4; ++r) av[r] = __shfl(alpha, g * 4 + r);
#pragma unroll
                for (int dt = 0; dt < 4; ++dt)
#pragma unroll
                    for (int r = 0; r < 4; ++r) acc[qf][dt][r] *= av[r];
                mrun[qf] = newm;
            }

            float tsum = 0.f;
#pragma unroll
            for (int kt = 0; kt < 4; ++kt)
#pragma unroll
                for (int r = 0; r < 4; ++r) {
                    p[kt][r] = __expf(p[kt][r] - mrun[qf]);
                    tsum += p[kt][r];
                }
            tsum += __shfl_xor(tsum, 16);
            tsum += __shfl_xor(tsum, 32);
            ssum[qf] += tsum;

            // pack P into PV A-fragments (no cross-lane needed by construction)
#pragma unroll
            for (int c = 0; c < 2; ++c) {
                union { u32 w[4]; bf16x8 v; } pu;
#pragma unroll
                for (int m = 0; m < 4; ++m) {
                    const int kt = 2 * c + (m >> 1);
                    pu.w[m] = pkbf(p[kt][2 * (m & 1)], p[kt][2 * (m & 1) + 1]);
                }
                pa[qf][c] = pu.v;
            }
        }

#pragma unroll
        for (int dt = 0; dt < 4; ++dt) {
            const int d = dt * 16 + lr;
            const int vx = skey(d);
#pragma unroll
            for (int c = 0; c < 2; ++c) {
                const bf16x8 vf = *(const bf16x8*)((const char*)vb + d * 128 + ((((c * 4) + g) ^ vx) << 4));
                acc[0][dt] = mfma16(pa[0][c], vf, acc[0][dt]);
                acc[1][dt] = mfma16(pa[1][c], vf, acc[1][dt]);
            }
        }

        asm volatile("s_waitcnt vmcnt(0)" ::: "memory");
        __syncthreads();
    }

#pragma unroll
    for (int qf = 0; qf < 2; ++qf) {
        const float inv = (ssum[qf] > 0.f) ? 1.f / ssum[qf] : 0.f;
        float iv[4];
#pragma unroll
        for (int r = 0; r < 4; ++r) iv[r] = __shfl(inv, g * 4 + r);
#pragma unroll
        for (int dt = 0; dt < 4; ++dt)
#pragma unroll
            for (int r = 0; r < 4; ++r) {
                const int q = q0 + qf * 16 + g * 4 + r;
                ctx[((size_t)b * L_ + q) * D_ + hoff + dt * 16 + lr] = (__bf16)(acc[qf][dt][r] * iv[r]);
            }
    }
}

extern "C" void kernel_launch(void* const* d_in, const int* in_sizes, int n_in,
                              void* d_out, int out_size, void* d_ws, size_t ws_size,
                              hipStream_t stream)
{
    const float* text    = (const float*)d_in[0];
    const float* regions = (const float*)d_in[1];
    const int*   mask    = (const int*)d_in[2];
    const float* Wq  = (const float*)d_in[3];
    const float* Aq  = (const float*)d_in[4];
    const float* Bq  = (const float*)d_in[5];
    const float* Wk  = (const float*)d_in[6];
    const float* Wv  = (const float*)d_in[7];
    const float* Av  = (const float*)d_in[8];
    const float* Bv  = (const float*)d_in[9];
    const float* Wo  = (const float*)d_in[10];
    const float* bo  = (const float*)d_in[11];
    const float* gq  = (const float*)d_in[12];
    const float* bq  = (const float*)d_in[13];
    const float* gkv = (const float*)d_in[14];
    const float* bkv = (const float*)d_in[15];

    const size_t BLD = (size_t)B_ * L_ * D_;
    const size_t BND = (size_t)B_ * N_ * D_;
    const size_t DD  = (size_t)D_ * D_;
    __bf16* ws   = (__bf16*)d_ws;
    __bf16* tq   = ws;                 // BLD
    __bf16* rk   = tq + BLD;           // BND
    __bf16* Qb   = rk + BND;           // BLD
    __bf16* Kb   = Qb + BLD;           // BND
    __bf16* Vt   = Kb + BND;           // BND
    __bf16* ctx  = Vt + BND;           // BLD
    __bf16* regb = ctx + BLD;          // BND
    __bf16* Weq  = regb + BND;         // DD
    __bf16* Wev  = Weq + DD;           // DD
    __bf16* Wkb  = Wev + DD;           // DD
    __bf16* Wob  = Wkb + DD;           // DD

    const int smB = 32768;  // dynamic LDS for gemm kernels

    weff_kernel<<<dim3(DD / 256), 256, 0, stream>>>(Wq, Bq, Aq, Weq);
    weff_kernel<<<dim3(DD / 256), 256, 0, stream>>>(Wv, Bv, Av, Wev);
    cast_kernel<<<dim3(DD / 1024), 256, 0, stream>>>(Wk, Wkb, (int)DD);
    cast_kernel<<<dim3(DD / 1024), 256, 0, stream>>>(Wo, Wob, (int)DD);
    cast_kernel<<<dim3(BND / 1024), 256, 0, stream>>>(regions, regb, (int)BND);
    ln_kernel<<<dim3(B_ * L_), 256, 0, stream>>>(text, gq, bq, tq);
    ln_kernel<<<dim3(B_ * N_), 256, 0, stream>>>(regions, gkv, bkv, rk);
    gemm_nt<3, __bf16><<<dim3((B_ * L_) / 128, D_ / 128), 256, smB, stream>>>(tq, Weq, Qb, nullptr, nullptr);
    gemm_kv<<<dim3(2 * (B_ * N_) / 128, D_ / 128), 256, smB, stream>>>(rk, Wkb, regb, Wev, Kb, Vt);
    attn_kernel<<<dim3(L_ / 128, H_, B_), 256, 0, stream>>>(Qb, Kb, Vt, mask, ctx);
    gemm_nt<2, float><<<dim3((B_ * L_) / 128, D_ / 128), 256, smB, stream>>>(ctx, Wob, (float*)d_out, text, bo);
}

// Round 6
// 208.010 us; speedup vs baseline: 2.8313x; 1.0087x over previous
//
#include <hip/hip_runtime.h>
#include <cstdint>
#include <cstddef>

#define B_  4
#define L_  4096
#define N_  1024
#define D_  768
#define H_  12
#define HD_ 64

typedef __bf16 bf16x4 __attribute__((ext_vector_type(4)));
typedef __bf16 bf16x8 __attribute__((ext_vector_type(8)));
typedef float  f32x4  __attribute__((ext_vector_type(4)));
typedef unsigned int u32;

#define QK_SCALE 0.18033688f   // 0.125 * log2(e): softmax done in exp2 domain

static __device__ __forceinline__ f32x4 mfma16(bf16x8 a, bf16x8 b, f32x4 c) {
    return __builtin_amdgcn_mfma_f32_16x16x32_bf16(a, b, c, 0, 0, 0);
}

static __device__ __forceinline__ void async_cp16(const __bf16* g, const __bf16* l) {
    __builtin_amdgcn_global_load_lds(
        (const __attribute__((address_space(1))) u32*)g,
        (__attribute__((address_space(3))) u32*)l, 16, 0, 0);
}

static __device__ __forceinline__ u32 pkbf(float lo, float hi) {
    union { __bf16 b[2]; u32 u; } r;
    r.b[0] = (__bf16)lo; r.b[1] = (__bf16)hi;
    return r.u;
}

// ---------------- fused prologue: LN(text), LN(regions), casts, weff ----------------

static __device__ __forceinline__ void ln_row(const float* __restrict__ xr,
                                              const float* __restrict__ g,
                                              const float* __restrict__ be,
                                              __bf16* __restrict__ yr)
{
    const int tid = threadIdx.x, lane = tid & 63, wid = tid >> 6;
    float4 v = make_float4(0.f, 0.f, 0.f, 0.f);
    if (tid < 192) v = *(const float4*)(xr + tid * 4);
    float s  = v.x + v.y + v.z + v.w;
    float s2 = v.x * v.x + v.y * v.y + v.z * v.z + v.w * v.w;
#pragma unroll
    for (int off = 32; off > 0; off >>= 1) {
        s  += __shfl_down(s, off);
        s2 += __shfl_down(s2, off);
    }
    __shared__ float red[8];
    if (lane == 0) { red[wid] = s; red[4 + wid] = s2; }
    __syncthreads();
    s  = red[0] + red[1] + red[2] + red[3];
    s2 = red[4] + red[5] + red[6] + red[7];
    const float mean = s * (1.f / D_);
    const float var  = s2 * (1.f / D_) - mean * mean;
    const float rstd = rsqrtf(var + 1e-5f);
    if (tid < 192) {
        const float4 gv = *(const float4*)(g + tid * 4);
        const float4 bv = *(const float4*)(be + tid * 4);
        bf16x4 o;
        o[0] = (__bf16)((v.x - mean) * rstd * gv.x + bv.x);
        o[1] = (__bf16)((v.y - mean) * rstd * gv.y + bv.y);
        o[2] = (__bf16)((v.z - mean) * rstd * gv.z + bv.z);
        o[3] = (__bf16)((v.w - mean) * rstd * gv.w + bv.w);
        *(bf16x4*)(yr + tid * 4) = o;
    }
}

static __device__ __forceinline__ void cast4(const float* __restrict__ in,
                                             __bf16* __restrict__ out, int blk)
{
    const int i = (blk * 256 + threadIdx.x) * 4;
    const float4 v = *(const float4*)(in + i);
    bf16x4 o;
    o[0] = (__bf16)v.x; o[1] = (__bf16)v.y; o[2] = (__bf16)v.z; o[3] = (__bf16)v.w;
    *(bf16x4*)(out + i) = o;
}

static __device__ __forceinline__ void weff4(const float* __restrict__ W,
                                             const float* __restrict__ Bm,
                                             const float* __restrict__ Am,
                                             __bf16* __restrict__ out, int blk)
{
    const int idx = (blk * 256 + threadIdx.x) * 4;
    const int o = idx / D_, i = idx - o * D_;
    const float4 w = *(const float4*)(W + idx);
    float sx = 0.f, sy = 0.f, sz = 0.f, sw = 0.f;
#pragma unroll
    for (int r = 0; r < 8; ++r) {
        const float b = Bm[o * 8 + r];
        const float4 a = *(const float4*)(Am + r * D_ + i);
        sx += b * a.x; sy += b * a.y; sz += b * a.z; sw += b * a.w;
    }
    bf16x4 ov;
    ov[0] = (__bf16)(w.x + 2.f * sx);
    ov[1] = (__bf16)(w.y + 2.f * sy);
    ov[2] = (__bf16)(w.z + 2.f * sz);
    ov[3] = (__bf16)(w.w + 2.f * sw);
    *(bf16x4*)(out + idx) = ov;
}

__global__ __launch_bounds__(256) void prologue_kernel(
    const float* __restrict__ text, const float* __restrict__ regions,
    const float* __restrict__ Wq, const float* __restrict__ Aq, const float* __restrict__ Bq,
    const float* __restrict__ Wv, const float* __restrict__ Av, const float* __restrict__ Bv,
    const float* __restrict__ Wk, const float* __restrict__ Wo,
    const float* __restrict__ gq, const float* __restrict__ bq,
    const float* __restrict__ gkv, const float* __restrict__ bkv,
    __bf16* __restrict__ tq, __bf16* __restrict__ rk, __bf16* __restrict__ regb,
    __bf16* __restrict__ Weq, __bf16* __restrict__ Wev,
    __bf16* __restrict__ Wkb, __bf16* __restrict__ Wob)
{
    int bx = blockIdx.x;
    if (bx < B_ * L_) { ln_row(text + (size_t)bx * D_, gq, bq, tq + (size_t)bx * D_); return; }
    bx -= B_ * L_;
    if (bx < B_ * N_) { ln_row(regions + (size_t)bx * D_, gkv, bkv, rk + (size_t)bx * D_); return; }
    bx -= B_ * N_;
    if (bx < 3072) { cast4(regions, regb, bx); return; }
    bx -= 3072;
    if (bx < 576) { weff4(Wq, Bq, Aq, Weq, bx); return; }
    bx -= 576;
    if (bx < 576) { weff4(Wv, Bv, Av, Wev, bx); return; }
    bx -= 576;
    if (bx < 576) { cast4(Wk, Wkb, bx); return; }
    bx -= 576;
    cast4(Wo, Wob, bx);
}

// ---------------- LDS-staged 128x128 GEMM (m97 structure) ----------------
// C[m][o] = sum_k A[m][k]*W[o][k]
// EPI==0: bf16 row-major | EPI==1: bf16 transposed (B,H,HD,N) | EPI==2: +resid+bias fp32 | EPI==3: *QK_SCALE bf16
template <int EPI, typename CT>
static __device__ __forceinline__ void gemm_body(__bf16* sm,
                                                 const __bf16* __restrict__ A,
                                                 const __bf16* __restrict__ W,
                                                 CT* __restrict__ C,
                                                 const float* __restrict__ resid,
                                                 const float* __restrict__ bias,
                                                 int mb0, int nb0)
{
    const int tid = threadIdx.x, wid = tid >> 6, lane = tid & 63;
    const int lr = lane & 15, g = lane >> 4;
    const int wm = wid >> 1, wn = wid & 1;

    auto stage = [&](int kb, int buf) {
        __bf16* as = sm + buf * 8192;
        __bf16* bs = as + 4096;
#pragma unroll
        for (int j = 0; j < 2; ++j) {
            const int s = wid * 64 + lane + j * 256;
            const int row = s >> 2, c16 = s & 3;
            const int dst = (wid * 64 + j * 256) * 8;
            async_cp16(A + (size_t)(mb0 + row) * D_ + kb * 32 + c16 * 8, as + dst);
            async_cp16(W + (size_t)(nb0 + row) * D_ + kb * 32 + c16 * 8, bs + dst);
        }
    };

    f32x4 acc[4][4] = {};

    stage(0, 0);
    asm volatile("s_waitcnt vmcnt(0)" ::: "memory");
    __syncthreads();

    for (int kb = 0; kb < D_ / 32; ++kb) {
        const int buf = kb & 1;
        if (kb < D_ / 32 - 1) stage(kb + 1, buf ^ 1);
        const __bf16* as = sm + buf * 8192;
        const __bf16* bs = as + 4096;
        bf16x8 av[4], wv[4];
#pragma unroll
        for (int mi = 0; mi < 4; ++mi)
            av[mi] = *(const bf16x8*)(as + (wm * 64 + mi * 16 + lr) * 32 + g * 8);
#pragma unroll
        for (int oi = 0; oi < 4; ++oi)
            wv[oi] = *(const bf16x8*)(bs + (wn * 64 + oi * 16 + lr) * 32 + g * 8);
        __builtin_amdgcn_s_setprio(1);
#pragma unroll
        for (int mi = 0; mi < 4; ++mi)
#pragma unroll
            for (int oi = 0; oi < 4; ++oi)
                acc[mi][oi] = mfma16(av[mi], wv[oi], acc[mi][oi]);
        __builtin_amdgcn_s_setprio(0);
        asm volatile("s_waitcnt vmcnt(0)" ::: "memory");
        __syncthreads();
    }

#pragma unroll
    for (int mi = 0; mi < 4; ++mi) {
#pragma unroll
        for (int oi = 0; oi < 4; ++oi) {
#pragma unroll
            for (int r = 0; r < 4; ++r) {
                const int m = mb0 + wm * 64 + mi * 16 + g * 4 + r;
                const int o = nb0 + wn * 64 + oi * 16 + lr;
                float v = acc[mi][oi][r];
                if (EPI == 2)
                    v += resid[(size_t)m * D_ + o] + bias[o];
                if (EPI == 3)
                    v *= QK_SCALE;
                if (EPI == 1) {
                    const size_t idx =
                        ((size_t)((m >> 10) * H_ + (o >> 6)) * HD_ + (o & 63)) * N_ + (m & (N_ - 1));
                    C[idx] = (CT)v;
                } else {
                    C[(size_t)m * D_ + o] = (CT)v;
                }
            }
        }
    }
}

// Fused Q+K+V projection GEMMs
__global__ __launch_bounds__(256) void gemm_qkv(const __bf16* __restrict__ tq,
                                                const __bf16* __restrict__ Weq,
                                                __bf16* __restrict__ Qb,
                                                const __bf16* __restrict__ rk,
                                                const __bf16* __restrict__ Wkb,
                                                __bf16* __restrict__ Kb,
                                                const __bf16* __restrict__ regb,
                                                const __bf16* __restrict__ Wev,
                                                __bf16* __restrict__ Vt)
{
    extern __shared__ __bf16 smem[];
    const int bx = blockIdx.x, ny = blockIdx.y * 128;
    if (bx < 128)      gemm_body<3, __bf16>(smem, tq,   Weq, Qb, nullptr, nullptr, bx * 128, ny);
    else if (bx < 160) gemm_body<0, __bf16>(smem, rk,   Wkb, Kb, nullptr, nullptr, (bx - 128) * 128, ny);
    else               gemm_body<1, __bf16>(smem, regb, Wev, Vt, nullptr, nullptr, (bx - 160) * 128, ny);
}

__global__ __launch_bounds__(256) void gemm_out(const __bf16* __restrict__ A,
                                                const __bf16* __restrict__ W,
                                                float* __restrict__ C,
                                                const float* __restrict__ resid,
                                                const float* __restrict__ bias)
{
    extern __shared__ __bf16 smem[];
    gemm_body<2, float>(smem, A, W, C, resid, bias, blockIdx.x * 128, blockIdx.y * 128);
}

// ---------------- flash attention ----------------
// Block = (b, h, 128 q), 4 waves x 32 q. Q pre-scaled by 0.125*log2e; softmax in exp2 domain.
// 3-buffer K/V pipeline, counted vmcnt (4 loads/stage), raw s_barrier.
// Q:(B,L,D) bf16, K:(B,N,D) bf16, Vt:(B,H,HD,N) bf16, mask:(B,N) int
__global__ __launch_bounds__(256, 3) void attn_kernel(const __bf16* __restrict__ Qb,
                                                      const __bf16* __restrict__ Kb,
                                                      const __bf16* __restrict__ Vt,
                                                      const int* __restrict__ mask,
                                                      __bf16* __restrict__ ctx)
{
    const int bq = blockIdx.x, h = blockIdx.y, b = blockIdx.z;
    const int tid = threadIdx.x, wid = tid >> 6, lane = tid & 63;
    const int lr = lane & 15, g = lane >> 4;

    __shared__ float maskadd[N_];
    __shared__ __align__(16) __bf16 kbuf[3][4096];   // 64 keys x 64 d, slot-swizzled
    __shared__ __align__(16) __bf16 vbuf[3][4096];   // 64 d x 64 keys, slot-swizzled

    for (int i = tid; i < N_; i += 256)
        maskadd[i] = (mask[b * N_ + i] != 0) ? 0.f : -1e30f;

    const int hoff = h * HD_;
    const int bN = b * N_;
    const size_t bhHD = ((size_t)b * H_ + h) * HD_;

    // slot-swizzle key: spreads the 16 concurrently-read rows over all 8 slots
    auto skey = [](int row) { return (row & 3) | (((row >> 3) & 1) << 2); };

    // staging: per-thread source pointers, advanced per tile; 4 loads per stage
    const int s0 = wid * 64 + lane, s1 = s0 + 256;
    const int row0 = s0 >> 3, row1 = s1 >> 3;
    const int ks0 = (s0 & 7) ^ skey(row0), ks1 = (s1 & 7) ^ skey(row1);
    const __bf16* kc0 = Kb + (size_t)(bN + row0) * D_ + hoff + ks0 * 8;
    const __bf16* kc1 = Kb + (size_t)(bN + row1) * D_ + hoff + ks1 * 8;
    const __bf16* vc0 = Vt + (bhHD + row0) * N_ + ks0 * 8;
    const __bf16* vc1 = Vt + (bhHD + row1) * N_ + ks1 * 8;
    const int d0 = wid * 512, d1 = wid * 512 + 2048;

    auto stage = [&](int bsel) {
        async_cp16(kc0, &kbuf[bsel][d0]);
        async_cp16(kc1, &kbuf[bsel][d1]);
        async_cp16(vc0, &vbuf[bsel][d0]);
        async_cp16(vc1, &vbuf[bsel][d1]);
        kc0 += 64 * D_; kc1 += 64 * D_; vc0 += 64; vc1 += 64;
    };

    const int q0 = bq * 128 + wid * 32;
    bf16x8 qa[2][2];
#pragma unroll
    for (int qf = 0; qf < 2; ++qf) {
        const __bf16* qptr = Qb + ((size_t)b * L_ + q0 + qf * 16 + lr) * D_ + hoff + g * 8;
        qa[qf][0] = *(const bf16x8*)(qptr);
        qa[qf][1] = *(const bf16x8*)(qptr + 32);
    }

    f32x4 acc[2][4] = {};
    float mrun[2] = {0.f, 0.f}, ssum[2] = {0.f, 0.f};

    stage(0); stage(1);
    asm volatile("s_waitcnt vmcnt(4) lgkmcnt(0)" ::: "memory");
    __builtin_amdgcn_s_barrier();

    int cb = 0, sb = 2;
    for (int t = 0; t < 16; ++t) {
        if (t < 14) { stage(sb); sb = (sb == 2) ? 0 : sb + 1; }

        const __bf16* kb = kbuf[cb];
        const __bf16* vb = vbuf[cb];
        cb = (cb == 2) ? 0 : cb + 1;

        // mask additive terms for this tile (same for both q-frags)
        f32x4 mv[4];
#pragma unroll
        for (int kt = 0; kt < 4; ++kt)
            mv[kt] = *(const f32x4*)&maskadd[t * 64 + (kt >> 1) * 32 + g * 8 + (kt & 1) * 4];

        // K fragments: rows permuted so lane's S values == its PV A-fragment keys
        bf16x8 kf[4][2];
#pragma unroll
        for (int kt = 0; kt < 4; ++kt) {
            const int row = (kt >> 1) * 32 + (lr >> 2) * 8 + (kt & 1) * 4 + (lr & 3);
            const int kx = skey(row);
#pragma unroll
            for (int kc = 0; kc < 2; ++kc)
                kf[kt][kc] = *(const bf16x8*)((const char*)kb + row * 128 + ((((kc * 4) + g) ^ kx) << 4));
        }

        bf16x8 pa[2][2];
#pragma unroll
        for (int qf = 0; qf < 2; ++qf) {
            // S^T = K·Q^T : lane holds q=lr, keys (kt>>1)*32 + g*8 + (kt&1)*4 + r
            f32x4 s4[4];
            __builtin_amdgcn_s_setprio(1);
#pragma unroll
            for (int kt = 0; kt < 4; ++kt) {
                f32x4 z = {};
                s4[kt] = mfma16(kf[kt][0], qa[qf][0], z);
                s4[kt] = mfma16(kf[kt][1], qa[qf][1], s4[kt]);
            }
            __builtin_amdgcn_s_setprio(0);

            float p[4][4];
            float pmax = -3e38f;
#pragma unroll
            for (int kt = 0; kt < 4; ++kt)
#pragma unroll
                for (int r = 0; r < 4; ++r) {
                    p[kt][r] = s4[kt][r] + mv[kt][r];
                    pmax = fmaxf(pmax, p[kt][r]);
                }
            pmax = fmaxf(pmax, __shfl_xor(pmax, 16));
            pmax = fmaxf(pmax, __shfl_xor(pmax, 32));

            if (__any(pmax > mrun[qf] + 8.f)) {       // defer-max: rare
                const float newm = fmaxf(mrun[qf], pmax);
                const float alpha = exp2f(mrun[qf] - newm);
                ssum[qf] *= alpha;
                float av[4];
#pragma unroll
                for (int r = 0; r < 4; ++r) av[r] = __shfl(alpha, g * 4 + r);
#pragma unroll
                for (int dt = 0; dt < 4; ++dt)
#pragma unroll
                    for (int r = 0; r < 4; ++r) acc[qf][dt][r] *= av[r];
                mrun[qf] = newm;
            }

            float tsum = 0.f;
#pragma unroll
            for (int kt = 0; kt < 4; ++kt)
#pragma unroll
                for (int r = 0; r < 4; ++r) {
                    p[kt][r] = exp2f(p[kt][r] - mrun[qf]);
                    tsum += p[kt][r];
                }
            tsum += __shfl_xor(tsum, 16);
            tsum += __shfl_xor(tsum, 32);
            ssum[qf] += tsum;

            // pack P into PV A-fragments (no cross-lane needed by construction)
#pragma unroll
            for (int c = 0; c < 2; ++c) {
                union { u32 w[4]; bf16x8 v; } pu;
#pragma unroll
                for (int m = 0; m < 4; ++m) {
                    const int kt = 2 * c + (m >> 1);
                    pu.w[m] = pkbf(p[kt][2 * (m & 1)], p[kt][2 * (m & 1) + 1]);
                }
                pa[qf][c] = pu.v;
            }
        }

        __builtin_amdgcn_s_setprio(1);
#pragma unroll
        for (int dt = 0; dt < 4; ++dt) {
            const int d = dt * 16 + lr;
            const int vx = skey(d);
#pragma unroll
            for (int c = 0; c < 2; ++c) {
                const bf16x8 vf = *(const bf16x8*)((const char*)vb + d * 128 + ((((c * 4) + g) ^ vx) << 4));
                acc[0][dt] = mfma16(pa[0][c], vf, acc[0][dt]);
                acc[1][dt] = mfma16(pa[1][c], vf, acc[1][dt]);
            }
        }
        __builtin_amdgcn_s_setprio(0);

        if (t < 15) {
            if (t < 14) asm volatile("s_waitcnt vmcnt(4)" ::: "memory");
            else        asm volatile("s_waitcnt vmcnt(0)" ::: "memory");
            __builtin_amdgcn_s_barrier();
        }
    }

#pragma unroll
    for (int qf = 0; qf < 2; ++qf) {
        const float inv = (ssum[qf] > 0.f) ? 1.f / ssum[qf] : 0.f;
        float iv[4];
#pragma unroll
        for (int r = 0; r < 4; ++r) iv[r] = __shfl(inv, g * 4 + r);
#pragma unroll
        for (int dt = 0; dt < 4; ++dt)
#pragma unroll
            for (int r = 0; r < 4; ++r) {
                const int q = q0 + qf * 16 + g * 4 + r;
                ctx[((size_t)b * L_ + q) * D_ + hoff + dt * 16 + lr] = (__bf16)(acc[qf][dt][r] * iv[r]);
            }
    }
}

extern "C" void kernel_launch(void* const* d_in, const int* in_sizes, int n_in,
                              void* d_out, int out_size, void* d_ws, size_t ws_size,
                              hipStream_t stream)
{
    const float* text    = (const float*)d_in[0];
    const float* regions = (const float*)d_in[1];
    const int*   mask    = (const int*)d_in[2];
    const float* Wq  = (const float*)d_in[3];
    const float* Aq  = (const float*)d_in[4];
    const float* Bq  = (const float*)d_in[5];
    const float* Wk  = (const float*)d_in[6];
    const float* Wv  = (const float*)d_in[7];
    const float* Av  = (const float*)d_in[8];
    const float* Bv  = (const float*)d_in[9];
    const float* Wo  = (const float*)d_in[10];
    const float* bo  = (const float*)d_in[11];
    const float* gq  = (const float*)d_in[12];
    const float* bq  = (const float*)d_in[13];
    const float* gkv = (const float*)d_in[14];
    const float* bkv = (const float*)d_in[15];

    const size_t BLD = (size_t)B_ * L_ * D_;
    const size_t BND = (size_t)B_ * N_ * D_;
    const size_t DD  = (size_t)D_ * D_;
    __bf16* ws   = (__bf16*)d_ws;
    __bf16* tq   = ws;                 // BLD
    __bf16* rk   = tq + BLD;           // BND
    __bf16* Qb   = rk + BND;           // BLD
    __bf16* Kb   = Qb + BLD;           // BND
    __bf16* Vt   = Kb + BND;           // BND
    __bf16* ctx  = Vt + BND;           // BLD
    __bf16* regb = ctx + BLD;          // BND
    __bf16* Weq  = regb + BND;         // DD
    __bf16* Wev  = Weq + DD;           // DD
    __bf16* Wkb  = Wev + DD;           // DD
    __bf16* Wob  = Wkb + DD;           // DD

    const int smB = 32768;  // dynamic LDS for gemm kernels
    const int nProBlocks = B_ * L_ + B_ * N_ + 3072 + 576 * 4;

    prologue_kernel<<<dim3(nProBlocks), 256, 0, stream>>>(
        text, regions, Wq, Aq, Bq, Wv, Av, Bv, Wk, Wo,
        gq, bq, gkv, bkv, tq, rk, regb, Weq, Wev, Wkb, Wob);
    gemm_qkv<<<dim3(192, D_ / 128), 256, smB, stream>>>(tq, Weq, Qb, rk, Wkb, Kb, regb, Wev, Vt);
    attn_kernel<<<dim3(L_ / 128, H_, B_), 256, 0, stream>>>(Qb, Kb, Vt, mask, ctx);
    gemm_out<<<dim3((B_ * L_) / 128, D_ / 128), 256, smB, stream>>>(ctx, Wob, (float*)d_out, text, bo);
}